// Round 1
// baseline (270.927 us; speedup 1.0000x reference)
//
#include <hip/hip_runtime.h>
#include <math.h>

#define BB 8
#define TT 16384
#define DD 128
#define DH 64

static __device__ __forceinline__ float4 ld4(const float* p) { return *(const float4*)p; }

// ---------------------------------------------------------------------------
// Kernel 1: binding logits -> chunk_start bits.
// Block = 256 thr, handles bind indices t in [blk*64, blk*64+63].
// Computes K[t] = x[t]@Wk, Q[t+1] = x[t+1]@Wq via shared x tile (65 rows, halo),
// dot>0 -> bound -> chunk_start[t+1]=0.
// ---------------------------------------------------------------------------
__global__ __launch_bounds__(256) void k_bind(
    const float* __restrict__ x, const float* __restrict__ Wk, const float* __restrict__ bk,
    const float* __restrict__ Wq, const float* __restrict__ bq, int* __restrict__ cstart)
{
    __shared__ float xs[DD][65];   // xs[d][m], m = 0..64 (65 rows incl. halo), stride 65 (odd -> low bank conflict)
    __shared__ float ws[32][128];  // W k-chunk: cols 0..63 = Wk, 64..127 = Wq
    const int b   = blockIdx.y;
    const int tb  = blockIdx.x * 64;
    const int tid = threadIdx.x;
    const int jg  = tid & 15;      // output col group (4 cols of K and 4 of Q)
    const int rg  = tid >> 4;      // row group (4 rows)

    // load x rows tb..tb+64 transposed into LDS (coalesced global, ~4-way LDS write conflict)
    for (int i = tid; i < 65 * 32; i += 256) {
        int r = i >> 5, c4 = (i & 31) * 4;
        float4 v = make_float4(0.f, 0.f, 0.f, 0.f);
        int trow = tb + r;
        if (trow < TT) v = ld4(x + ((size_t)b * TT + trow) * DD + c4);
        xs[c4 + 0][r] = v.x; xs[c4 + 1][r] = v.y; xs[c4 + 2][r] = v.z; xs[c4 + 3][r] = v.w;
    }

    float ak[4][4] = {{0.f}}, aq[4][4] = {{0.f}};
    for (int k0 = 0; k0 < DD; k0 += 32) {
        __syncthreads();
        for (int i = tid; i < 32 * 32; i += 256) {
            int kk = i >> 5, c4 = i & 31;
            if (c4 < 16) *(float4*)&ws[kk][c4 * 4]             = ld4(Wk + (k0 + kk) * DH + c4 * 4);
            else         *(float4*)&ws[kk][64 + (c4 - 16) * 4] = ld4(Wq + (k0 + kk) * DH + (c4 - 16) * 4);
        }
        __syncthreads();
        #pragma unroll
        for (int kk = 0; kk < 32; ++kk) {
            float a[5];
            #pragma unroll
            for (int r = 0; r < 5; ++r) a[r] = xs[k0 + kk][rg * 4 + r];
            float wk[4], wq[4];
            *(float4*)wk = *(const float4*)&ws[kk][jg * 4];
            *(float4*)wq = *(const float4*)&ws[kk][64 + jg * 4];
            #pragma unroll
            for (int r = 0; r < 4; ++r) {
                #pragma unroll
                for (int c = 0; c < 4; ++c) {
                    ak[r][c] = fmaf(a[r],     wk[c], ak[r][c]);   // K row t = tb+rg*4+r
                    aq[r][c] = fmaf(a[r + 1], wq[c], aq[r][c]);   // Q row t+1
                }
            }
        }
    }

    float bkv[4], bqv[4];
    *(float4*)bkv = ld4(bk + jg * 4);
    *(float4*)bqv = ld4(bq + jg * 4);
    #pragma unroll
    for (int r = 0; r < 4; ++r) {
        float dot = 0.f;
        #pragma unroll
        for (int c = 0; c < 4; ++c) dot += (ak[r][c] + bkv[c]) * (aq[r][c] + bqv[c]);
        #pragma unroll
        for (int m = 1; m < 16; m <<= 1) dot += __shfl_xor(dot, m, 16);
        if (jg == 0) {
            int t = tb + rg * 4 + r;
            if (t <= TT - 2) cstart[b * TT + t + 1] = (dot > 0.f) ? 0 : 1;
        }
    }
    if (blockIdx.x == 0 && tid == 0) cstart[b * TT] = 1;
}

// ---------------------------------------------------------------------------
// Kernel 2: per-batch inclusive scan of chunk_start -> seg; also chunk start
// token index table cs[b][c] and chunk count numC[b]. cstart may alias seg
// (each thread reads only its own 16 elements before writing them).
// ---------------------------------------------------------------------------
__global__ __launch_bounds__(1024) void k_scan(const int* __restrict__ cstart,
    int* __restrict__ seg, int* __restrict__ cs, int* __restrict__ numC)
{
    __shared__ int lds[1024];
    const int b = blockIdx.x, tid = threadIdx.x;
    const int base = b * TT + tid * 16;
    int v[16];
    #pragma unroll
    for (int i = 0; i < 4; ++i) {
        int4 q = *(const int4*)(cstart + base + i * 4);
        v[i * 4 + 0] = q.x; v[i * 4 + 1] = q.y; v[i * 4 + 2] = q.z; v[i * 4 + 3] = q.w;
    }
    int s[16]; int run = 0;
    #pragma unroll
    for (int i = 0; i < 16; ++i) { run += v[i]; s[i] = run; }
    lds[tid] = run;
    __syncthreads();
    for (int off = 1; off < 1024; off <<= 1) {
        int t = (tid >= off) ? lds[tid - off] : 0;
        __syncthreads();
        lds[tid] += t;
        __syncthreads();
    }
    const int excl = lds[tid] - run;
    #pragma unroll
    for (int i = 0; i < 16; ++i) {
        int sg = excl + s[i] - 1;
        seg[base + i] = sg;
        if (v[i]) cs[b * (TT + 1) + sg] = tid * 16 + i;   // chunk sg starts at this token
    }
    if (tid == 0) {
        int tot = lds[1023];
        numC[b] = tot;
        cs[b * (TT + 1) + tot] = TT;                      // sentinel
    }
}

// ---------------------------------------------------------------------------
// Kernel 3a: chunk means. One wave per chunk (chunks are contiguous token
// ranges). lane holds 2 of the 128 dims.
// ---------------------------------------------------------------------------
__global__ __launch_bounds__(256) void k_mean(const float* __restrict__ x,
    const int* __restrict__ cs, const int* __restrict__ numC, float* __restrict__ cm)
{
    const int w    = blockIdx.x * 4 + (threadIdx.x >> 6);
    const int lane = threadIdx.x & 63;
    const int b    = w >> 14;        // / TT
    const int c    = w & (TT - 1);
    if (c >= numC[b]) return;
    const int t0 = cs[b * (TT + 1) + c], t1 = cs[b * (TT + 1) + c + 1];
    float sx = 0.f, sy = 0.f;
    const float* xp = x + ((size_t)b * TT + t0) * DD + lane * 2;
    for (int t = t0; t < t1; ++t, xp += DD) { sx += xp[0]; sy += xp[1]; }
    const float inv = 1.f / (float)(t1 - t0);
    float* o = cm + ((size_t)b * TT + c) * DD + lane * 2;
    o[0] = sx * inv; o[1] = sy * inv;
}

// ---------------------------------------------------------------------------
// Kernel 3b helper: C[64x128] = A(as_, transposed in LDS) @ W + bias.
// Thread owns rows rg*4..+3, cols jg*4..+3 and 64+jg*4..+3.
// Starts with __syncthreads() (covers prior LDS writes).
// ---------------------------------------------------------------------------
__device__ __forceinline__ void gemm_tile(float acc[4][8], const float (*A)[65],
    float (*ws)[128], const float* __restrict__ W, const float* __restrict__ bias,
    int tid, int jg, int rg)
{
    float blo[4], bhi[4];
    *(float4*)blo = ld4(bias + jg * 4);
    *(float4*)bhi = ld4(bias + 64 + jg * 4);
    #pragma unroll
    for (int r = 0; r < 4; ++r) {
        #pragma unroll
        for (int c = 0; c < 4; ++c) { acc[r][c] = blo[c]; acc[r][c + 4] = bhi[c]; }
    }
    for (int k0 = 0; k0 < DD; k0 += 32) {
        __syncthreads();
        for (int i = tid; i < 32 * 32; i += 256) {
            int kk = i >> 5, c4 = i & 31;
            *(float4*)&ws[kk][c4 * 4] = ld4(W + (k0 + kk) * DD + c4 * 4);
        }
        __syncthreads();
        #pragma unroll
        for (int kk = 0; kk < 32; ++kk) {
            float a[4];
            #pragma unroll
            for (int r = 0; r < 4; ++r) a[r] = A[k0 + kk][rg * 4 + r];
            float wl[4], wh[4];
            *(float4*)wl = *(const float4*)&ws[kk][jg * 4];
            *(float4*)wh = *(const float4*)&ws[kk][64 + jg * 4];
            #pragma unroll
            for (int r = 0; r < 4; ++r) {
                #pragma unroll
                for (int c = 0; c < 4; ++c) {
                    acc[r][c]     = fmaf(a[r], wl[c], acc[r][c]);
                    acc[r][c + 4] = fmaf(a[r], wh[c], acc[r][c + 4]);
                }
            }
        }
    }
}

// ---------------------------------------------------------------------------
// Kernel 3b: per-chunk MLP: Linear->LN->ReLU->Linear->Linear->sigmoid.
// Block handles 64 chunk rows; gate written in place over cm.
// ---------------------------------------------------------------------------
__global__ __launch_bounds__(256) void k_mlp(
    const float* __restrict__ Wa1, const float* __restrict__ ba1,
    const float* __restrict__ ln_g, const float* __restrict__ ln_b,
    const float* __restrict__ Wa2, const float* __restrict__ ba2,
    const float* __restrict__ Wd, const float* __restrict__ bd,
    const int* __restrict__ numC, float* __restrict__ cm)
{
    __shared__ float As[DD][65];
    __shared__ float ws[32][128];
    const int b  = blockIdx.y;
    const int nC = numC[b];
    const int c0 = blockIdx.x * 64;
    if (c0 >= nC) return;                       // uniform early-exit (before any barrier)
    const int tid = threadIdx.x;
    const int jg = tid & 15, rg = tid >> 4;

    for (int i = tid; i < 64 * 32; i += 256) {  // A tile: cm rows c0..c0+63 transposed
        int r = i >> 5, c4 = (i & 31) * 4;
        float4 v = make_float4(0.f, 0.f, 0.f, 0.f);
        if (c0 + r < nC) v = ld4(cm + ((size_t)b * TT + c0 + r) * DD + c4);
        As[c4 + 0][r] = v.x; As[c4 + 1][r] = v.y; As[c4 + 2][r] = v.z; As[c4 + 3][r] = v.w;
    }

    float acc[4][8];
    // ---- h = cm @ Wa1 + ba1 ----
    gemm_tile(acc, As, ws, Wa1, ba1, tid, jg, rg);

    // ---- LayerNorm (biased var, two-pass) + ReLU ----
    float mu[4], rstd[4];
    #pragma unroll
    for (int r = 0; r < 4; ++r) {
        float sm = 0.f;
        #pragma unroll
        for (int c = 0; c < 8; ++c) sm += acc[r][c];
        #pragma unroll
        for (int m = 1; m < 16; m <<= 1) sm += __shfl_xor(sm, m, 16);
        mu[r] = sm * (1.f / 128.f);
        float vs = 0.f;
        #pragma unroll
        for (int c = 0; c < 8; ++c) { float d = acc[r][c] - mu[r]; vs += d * d; }
        #pragma unroll
        for (int m = 1; m < 16; m <<= 1) vs += __shfl_xor(vs, m, 16);
        rstd[r] = rsqrtf(vs * (1.f / 128.f) + 1e-5f);
    }
    float gl[4], gh[4], bl[4], bh[4];
    *(float4*)gl = ld4(ln_g + jg * 4); *(float4*)gh = ld4(ln_g + 64 + jg * 4);
    *(float4*)bl = ld4(ln_b + jg * 4); *(float4*)bh = ld4(ln_b + 64 + jg * 4);
    __syncthreads();                            // all GEMM1 A-reads done before overwrite
    #pragma unroll
    for (int r = 0; r < 4; ++r) {
        #pragma unroll
        for (int c = 0; c < 4; ++c) {
            float h1 = fmaf((acc[r][c]     - mu[r]) * rstd[r], gl[c], bl[c]);
            float h2 = fmaf((acc[r][c + 4] - mu[r]) * rstd[r], gh[c], bh[c]);
            As[jg * 4 + c][rg * 4 + r]      = fmaxf(h1, 0.f);
            As[64 + jg * 4 + c][rg * 4 + r] = fmaxf(h2, 0.f);
        }
    }

    // ---- agg = relu(h) @ Wa2 + ba2 ----
    gemm_tile(acc, As, ws, Wa2, ba2, tid, jg, rg);
    __syncthreads();
    #pragma unroll
    for (int r = 0; r < 4; ++r) {
        #pragma unroll
        for (int c = 0; c < 4; ++c) {
            As[jg * 4 + c][rg * 4 + r]      = acc[r][c];
            As[64 + jg * 4 + c][rg * 4 + r] = acc[r][c + 4];
        }
    }

    // ---- infl = agg @ Wd + bd; gate = sigmoid(infl), in-place into cm ----
    gemm_tile(acc, As, ws, Wd, bd, tid, jg, rg);
    #pragma unroll
    for (int r = 0; r < 4; ++r) {
        int c = c0 + rg * 4 + r;
        if (c < nC) {
            float g[8];
            #pragma unroll
            for (int q = 0; q < 8; ++q) g[q] = 1.f / (1.f + __expf(-acc[r][q]));
            float* dst = cm + ((size_t)b * TT + c) * DD;
            *(float4*)(dst + jg * 4)      = *(float4*)&g[0];
            *(float4*)(dst + 64 + jg * 4) = *(float4*)&g[4];
        }
    }
}

// ---------------------------------------------------------------------------
// Kernel 4: out[t] = fma(x[t], gate[seg[t]], x[t])
// ---------------------------------------------------------------------------
__global__ __launch_bounds__(256) void k_out(const float* __restrict__ x,
    const int* __restrict__ seg, const float* __restrict__ gate, float* __restrict__ out)
{
    const size_t idx = (size_t)blockIdx.x * 256 + threadIdx.x;  // one float4 each
    const size_t tok = idx >> 5;
    const int d4 = (int)(idx & 31);
    const int b  = (int)(tok >> 14);
    const int sg = seg[tok];
    float4 g  = ld4(gate + (((size_t)b << 14) + sg) * DD + d4 * 4);
    float4 xv = ld4(x + tok * DD + (size_t)d4 * 4);
    float4 o;
    o.x = fmaf(xv.x, g.x, xv.x);
    o.y = fmaf(xv.y, g.y, xv.y);
    o.z = fmaf(xv.z, g.z, xv.z);
    o.w = fmaf(xv.w, g.w, xv.w);
    *(float4*)(out + idx * 4) = o;
}

extern "C" void kernel_launch(void* const* d_in, const int* in_sizes, int n_in,
                              void* d_out, int out_size, void* d_ws, size_t ws_size,
                              hipStream_t stream)
{
    (void)in_sizes; (void)n_in; (void)out_size; (void)ws_size;
    const float* x    = (const float*)d_in[0];
    const float* Wk   = (const float*)d_in[1];
    const float* bk   = (const float*)d_in[2];
    const float* Wq   = (const float*)d_in[3];
    const float* bq   = (const float*)d_in[4];
    const float* Wa1  = (const float*)d_in[5];
    const float* ba1  = (const float*)d_in[6];
    const float* ln_g = (const float*)d_in[7];
    const float* ln_b = (const float*)d_in[8];
    const float* Wa2  = (const float*)d_in[9];
    const float* ba2  = (const float*)d_in[10];
    const float* Wd   = (const float*)d_in[11];
    const float* bd   = (const float*)d_in[12];
    float* out = (float*)d_out;

    // ws layout: cm (B*T*D f32, reused as gate) | seg (B*T i32, also holds bind bits) | cs | numC
    char* ws = (char*)d_ws;
    float* cm = (float*)ws;
    int* seg  = (int*)(ws + (size_t)BB * TT * DD * 4);
    int* cs   = seg + BB * TT;
    int* numC = cs + BB * (TT + 1);

    k_bind<<<dim3(256, BB), 256, 0, stream>>>(x, Wk, bk, Wq, bq, seg);
    k_scan<<<dim3(BB), 1024, 0, stream>>>(seg, seg, cs, numC);
    k_mean<<<dim3(BB * TT / 4), 256, 0, stream>>>(x, cs, numC, cm);
    k_mlp<<<dim3(TT / 64, BB), 256, 0, stream>>>(Wa1, ba1, ln_g, ln_b, Wa2, ba2, Wd, bd, numC, cm);
    k_out<<<dim3(BB * TT * DD / (256 * 4)), 256, 0, stream>>>(x, seg, cm, out);
}

// Round 2
// 177.596 us; speedup vs baseline: 1.5255x; 1.5255x over previous
//
#include <hip/hip_runtime.h>
#include <math.h>

#define BB 8
#define TT 16384
#define DD 128
#define DH 64

typedef short short8 __attribute__((ext_vector_type(8)));
typedef float f32x4  __attribute__((ext_vector_type(4)));

static __device__ __forceinline__ float4 ld4(const float* p) { return *(const float4*)p; }

// bf16 round-to-nearest-even, manual (no API dependence)
static __device__ __forceinline__ uint f2bf(float x) {
    uint u = __float_as_uint(x);
    return (u + 0x7FFFu + ((u >> 16) & 1u)) >> 16;
}
// pack value x ~= hi + lo (both bf16) into u32 = (hi<<16)|lo
static __device__ __forceinline__ uint packhl(float x) {
    uint hb = f2bf(x);
    float hf = __uint_as_float(hb << 16);
    uint lb = f2bf(x - hf);
    return (hb << 16) | lb;
}

// ---------------------------------------------------------------------------
// Kernel 1: binding logits -> chunk_start bits. (unchanged, fp32: sign-exact)
// ---------------------------------------------------------------------------
__global__ __launch_bounds__(256) void k_bind(
    const float* __restrict__ x, const float* __restrict__ Wk, const float* __restrict__ bk,
    const float* __restrict__ Wq, const float* __restrict__ bq, int* __restrict__ cstart)
{
    __shared__ float xs[DD][65];
    __shared__ float ws[32][128];
    const int b   = blockIdx.y;
    const int tb  = blockIdx.x * 64;
    const int tid = threadIdx.x;
    const int jg  = tid & 15;
    const int rg  = tid >> 4;

    for (int i = tid; i < 65 * 32; i += 256) {
        int r = i >> 5, c4 = (i & 31) * 4;
        float4 v = make_float4(0.f, 0.f, 0.f, 0.f);
        int trow = tb + r;
        if (trow < TT) v = ld4(x + ((size_t)b * TT + trow) * DD + c4);
        xs[c4 + 0][r] = v.x; xs[c4 + 1][r] = v.y; xs[c4 + 2][r] = v.z; xs[c4 + 3][r] = v.w;
    }

    float ak[4][4] = {{0.f}}, aq[4][4] = {{0.f}};
    for (int k0 = 0; k0 < DD; k0 += 32) {
        __syncthreads();
        for (int i = tid; i < 32 * 32; i += 256) {
            int kk = i >> 5, c4 = i & 31;
            if (c4 < 16) *(float4*)&ws[kk][c4 * 4]             = ld4(Wk + (k0 + kk) * DH + c4 * 4);
            else         *(float4*)&ws[kk][64 + (c4 - 16) * 4] = ld4(Wq + (k0 + kk) * DH + (c4 - 16) * 4);
        }
        __syncthreads();
        #pragma unroll
        for (int kk = 0; kk < 32; ++kk) {
            float a[5];
            #pragma unroll
            for (int r = 0; r < 5; ++r) a[r] = xs[k0 + kk][rg * 4 + r];
            float wk[4], wq[4];
            *(float4*)wk = *(const float4*)&ws[kk][jg * 4];
            *(float4*)wq = *(const float4*)&ws[kk][64 + jg * 4];
            #pragma unroll
            for (int r = 0; r < 4; ++r) {
                #pragma unroll
                for (int c = 0; c < 4; ++c) {
                    ak[r][c] = fmaf(a[r],     wk[c], ak[r][c]);
                    aq[r][c] = fmaf(a[r + 1], wq[c], aq[r][c]);
                }
            }
        }
    }

    float bkv[4], bqv[4];
    *(float4*)bkv = ld4(bk + jg * 4);
    *(float4*)bqv = ld4(bq + jg * 4);
    #pragma unroll
    for (int r = 0; r < 4; ++r) {
        float dot = 0.f;
        #pragma unroll
        for (int c = 0; c < 4; ++c) dot += (ak[r][c] + bkv[c]) * (aq[r][c] + bqv[c]);
        #pragma unroll
        for (int m = 1; m < 16; m <<= 1) dot += __shfl_xor(dot, m, 16);
        if (jg == 0) {
            int t = tb + rg * 4 + r;
            if (t <= TT - 2) cstart[b * TT + t + 1] = (dot > 0.f) ? 0 : 1;
        }
    }
    if (blockIdx.x == 0 && tid == 0) cstart[b * TT] = 1;
}

// ---------------------------------------------------------------------------
// Kernel 2: per-batch scan -> seg, chunk-start table, counts. (unchanged)
// ---------------------------------------------------------------------------
__global__ __launch_bounds__(1024) void k_scan(const int* __restrict__ cstart,
    int* __restrict__ seg, int* __restrict__ cs, int* __restrict__ numC)
{
    __shared__ int lds[1024];
    const int b = blockIdx.x, tid = threadIdx.x;
    const int base = b * TT + tid * 16;
    int v[16];
    #pragma unroll
    for (int i = 0; i < 4; ++i) {
        int4 q = *(const int4*)(cstart + base + i * 4);
        v[i * 4 + 0] = q.x; v[i * 4 + 1] = q.y; v[i * 4 + 2] = q.z; v[i * 4 + 3] = q.w;
    }
    int s[16]; int run = 0;
    #pragma unroll
    for (int i = 0; i < 16; ++i) { run += v[i]; s[i] = run; }
    lds[tid] = run;
    __syncthreads();
    for (int off = 1; off < 1024; off <<= 1) {
        int t = (tid >= off) ? lds[tid - off] : 0;
        __syncthreads();
        lds[tid] += t;
        __syncthreads();
    }
    const int excl = lds[tid] - run;
    #pragma unroll
    for (int i = 0; i < 16; ++i) {
        int sg = excl + s[i] - 1;
        seg[base + i] = sg;
        if (v[i]) cs[b * (TT + 1) + sg] = tid * 16 + i;
    }
    if (tid == 0) {
        int tot = lds[1023];
        numC[b] = tot;
        cs[b * (TT + 1) + tot] = TT;
    }
}

// ---------------------------------------------------------------------------
// Kernel 3a: chunk means. (unchanged)
// ---------------------------------------------------------------------------
__global__ __launch_bounds__(256) void k_mean(const float* __restrict__ x,
    const int* __restrict__ cs, const int* __restrict__ numC, float* __restrict__ cm)
{
    const int w    = blockIdx.x * 4 + (threadIdx.x >> 6);
    const int lane = threadIdx.x & 63;
    const int b    = w >> 14;
    const int c    = w & (TT - 1);
    if (c >= numC[b]) return;
    const int t0 = cs[b * (TT + 1) + c], t1 = cs[b * (TT + 1) + c + 1];
    float sx = 0.f, sy = 0.f;
    const float* xp = x + ((size_t)b * TT + t0) * DD + lane * 2;
    for (int t = t0; t < t1; ++t, xp += DD) { sx += xp[0]; sy += xp[1]; }
    const float inv = 1.f / (float)(t1 - t0);
    float* o = cm + ((size_t)b * TT + c) * DD + lane * 2;
    o[0] = sx * inv; o[1] = sy * inv;
}

// ---------------------------------------------------------------------------
// Kernel W-prep: weights fp32 -> bf16 MFMA B-fragment layout.
// Frag (ly, nt, kb): lane l, elem e holds W[kb*32 + (l>>4)*8 + e][nt*16 + (l&15)]
// stored contiguously so k_mlp's load is one coalesced 16B/lane read.
// ---------------------------------------------------------------------------
__global__ __launch_bounds__(64) void k_wprep(
    const float* __restrict__ Wa1, const float* __restrict__ Wa2,
    const float* __restrict__ Wd, ushort* __restrict__ wf)
{
    const int l  = threadIdx.x;
    const int nt = blockIdx.x & 7;
    const int kb = blockIdx.x >> 3;
    const int ly = blockIdx.y;
    const float* W = (ly == 0) ? Wa1 : (ly == 1) ? Wa2 : Wd;
    const int n  = nt * 16 + (l & 15);
    const int k0 = kb * 32 + (l >> 4) * 8;
    short8 v;
    #pragma unroll
    for (int e = 0; e < 8; ++e) v[e] = (short)(ushort)f2bf(W[(k0 + e) * DD + n]);
    *(short8*)(wf + (size_t)(((ly * 8 + nt) * 4 + kb) * 64 + l) * 8) = v;
}

// ---------------------------------------------------------------------------
// k_mlp GEMM helper: acc[8] (16x128 per wave) += A(split hi+lo) @ W_bf16.
// A rows packed (hi<<16|lo) in LDS; 2 MFMAs per (kstep, coltile).
// ---------------------------------------------------------------------------
__device__ __forceinline__ void mlp_gemm(f32x4 acc[8], const uint (*As)[132],
    const ushort* __restrict__ wl, int m, int g, int l)
{
    #pragma unroll
    for (int nt = 0; nt < 8; ++nt) acc[nt] = (f32x4){0.f, 0.f, 0.f, 0.f};
    #pragma unroll
    for (int kb = 0; kb < 4; ++kb) {
        short8 bh[8];
        #pragma unroll
        for (int nt = 0; nt < 8; ++nt)
            bh[nt] = *(const short8*)(wl + (size_t)((nt * 4 + kb) * 64 + l) * 8);
        uint4 p0 = *(const uint4*)&As[m][kb * 32 + g * 8];
        uint4 p1 = *(const uint4*)&As[m][kb * 32 + g * 8 + 4];
        uint pp[8] = {p0.x, p0.y, p0.z, p0.w, p1.x, p1.y, p1.z, p1.w};
        union { uint u[4]; short8 s; } ah, al;
        #pragma unroll
        for (int j = 0; j < 4; ++j) {
            ah.u[j] = (pp[2 * j] >> 16)      | (pp[2 * j + 1] & 0xFFFF0000u);
            al.u[j] = (pp[2 * j] & 0xFFFFu)  | (pp[2 * j + 1] << 16);
        }
        #pragma unroll
        for (int nt = 0; nt < 8; ++nt) {
            acc[nt] = __builtin_amdgcn_mfma_f32_16x16x32_bf16(ah.s, bh[nt], acc[nt], 0, 0, 0);
            acc[nt] = __builtin_amdgcn_mfma_f32_16x16x32_bf16(al.s, bh[nt], acc[nt], 0, 0, 0);
        }
    }
}

// ---------------------------------------------------------------------------
// Kernel 3b: per-chunk MLP via MFMA. Block = 64 chunk rows, 4 waves, wave w
// owns rows w*16..w*16+15 (all 128 cols). Gate written in place over cm.
// C/D layout: col = lane&15 (+nt*16), row = (lane>>4)*4 + reg (verified m89).
// ---------------------------------------------------------------------------
__global__ __launch_bounds__(256) void k_mlp(
    const float* __restrict__ ba1, const float* __restrict__ ln_g, const float* __restrict__ ln_b,
    const float* __restrict__ ba2, const float* __restrict__ bd,
    const ushort* __restrict__ wf, const int* __restrict__ numC, float* __restrict__ cm)
{
    __shared__ uint As[64][132];   // packed bf16 (hi<<16|lo); stride 132 words: frag reads 2-way max
    const int b  = blockIdx.y;
    const int nC = numC[b];
    const int c0 = blockIdx.x * 64;
    if (c0 >= nC) return;
    const int tid  = threadIdx.x;
    const int wv   = tid >> 6;
    const int l    = tid & 63;
    const int lo16 = l & 15;
    const int g    = l >> 4;
    const int m    = wv * 16 + lo16;          // A-row for frag reads

    // stage cm rows -> packed hi/lo bf16
    for (int i = tid; i < 64 * 32; i += 256) {
        int r = i >> 5, c4 = (i & 31) * 4;
        float4 v = make_float4(0.f, 0.f, 0.f, 0.f);
        if (c0 + r < nC) v = ld4(cm + ((size_t)b * TT + c0 + r) * DD + c4);
        uint4 pk;
        pk.x = packhl(v.x); pk.y = packhl(v.y); pk.z = packhl(v.z); pk.w = packhl(v.w);
        *(uint4*)&As[r][c4] = pk;
    }
    __syncthreads();

    f32x4 acc[8];

    // ---- layer 1: h = cm @ Wa1 + ba1, LayerNorm, ReLU ----
    mlp_gemm(acc, As, wf, m, g, l);
    float bia[8];
    #pragma unroll
    for (int nt = 0; nt < 8; ++nt) bia[nt] = ba1[nt * 16 + lo16];
    #pragma unroll
    for (int nt = 0; nt < 8; ++nt)
        #pragma unroll
        for (int i = 0; i < 4; ++i) acc[nt][i] += bia[nt];

    float mu_[4], rs_[4];
    #pragma unroll
    for (int i = 0; i < 4; ++i) {
        float sm = 0.f;
        #pragma unroll
        for (int nt = 0; nt < 8; ++nt) sm += acc[nt][i];
        #pragma unroll
        for (int k = 1; k < 16; k <<= 1) sm += __shfl_xor(sm, k, 16);
        mu_[i] = sm * (1.f / 128.f);
        float vs = 0.f;
        #pragma unroll
        for (int nt = 0; nt < 8; ++nt) { float d = acc[nt][i] - mu_[i]; vs += d * d; }
        #pragma unroll
        for (int k = 1; k < 16; k <<= 1) vs += __shfl_xor(vs, k, 16);
        rs_[i] = rsqrtf(vs * (1.f / 128.f) + 1e-5f);
    }
    float gam[8], bet[8];
    #pragma unroll
    for (int nt = 0; nt < 8; ++nt) { gam[nt] = ln_g[nt * 16 + lo16]; bet[nt] = ln_b[nt * 16 + lo16]; }

    __syncthreads();                          // all layer-1 A-reads done
    #pragma unroll
    for (int nt = 0; nt < 8; ++nt)
        #pragma unroll
        for (int i = 0; i < 4; ++i) {
            float h = fmaf((acc[nt][i] - mu_[i]) * rs_[i], gam[nt], bet[nt]);
            As[wv * 16 + g * 4 + i][nt * 16 + lo16] = packhl(fmaxf(h, 0.f));
        }
    __syncthreads();

    // ---- layer 2: agg = relu(h) @ Wa2 + ba2 ----
    mlp_gemm(acc, As, wf + 32 * 64 * 8, m, g, l);
    #pragma unroll
    for (int nt = 0; nt < 8; ++nt) bia[nt] = ba2[nt * 16 + lo16];
    __syncthreads();
    #pragma unroll
    for (int nt = 0; nt < 8; ++nt)
        #pragma unroll
        for (int i = 0; i < 4; ++i)
            As[wv * 16 + g * 4 + i][nt * 16 + lo16] = packhl(acc[nt][i] + bia[nt]);
    __syncthreads();

    // ---- layer 3: infl = agg @ Wd + bd; gate = sigmoid ----
    mlp_gemm(acc, As, wf + 2 * 32 * 64 * 8, m, g, l);
    #pragma unroll
    for (int nt = 0; nt < 8; ++nt) bia[nt] = bd[nt * 16 + lo16];
    #pragma unroll
    for (int i = 0; i < 4; ++i) {
        int row = c0 + wv * 16 + g * 4 + i;
        if (row < nC) {
            float* dst = cm + ((size_t)b * TT + row) * DD + lo16;
            #pragma unroll
            for (int nt = 0; nt < 8; ++nt) {
                float z = acc[nt][i] + bia[nt];
                dst[nt * 16] = 1.f / (1.f + __expf(-z));
            }
        }
    }
}

// ---------------------------------------------------------------------------
// Kernel 4: out[t] = fma(x[t], gate[seg[t]], x[t])  (unchanged)
// ---------------------------------------------------------------------------
__global__ __launch_bounds__(256) void k_out(const float* __restrict__ x,
    const int* __restrict__ seg, const float* __restrict__ gate, float* __restrict__ out)
{
    const size_t idx = (size_t)blockIdx.x * 256 + threadIdx.x;
    const size_t tok = idx >> 5;
    const int d4 = (int)(idx & 31);
    const int b  = (int)(tok >> 14);
    const int sg = seg[tok];
    float4 gv = ld4(gate + (((size_t)b << 14) + sg) * DD + d4 * 4);
    float4 xv = ld4(x + tok * DD + (size_t)d4 * 4);
    float4 o;
    o.x = fmaf(xv.x, gv.x, xv.x);
    o.y = fmaf(xv.y, gv.y, xv.y);
    o.z = fmaf(xv.z, gv.z, xv.z);
    o.w = fmaf(xv.w, gv.w, xv.w);
    *(float4*)(out + idx * 4) = o;
}

extern "C" void kernel_launch(void* const* d_in, const int* in_sizes, int n_in,
                              void* d_out, int out_size, void* d_ws, size_t ws_size,
                              hipStream_t stream)
{
    (void)in_sizes; (void)n_in; (void)out_size; (void)ws_size;
    const float* x    = (const float*)d_in[0];
    const float* Wk   = (const float*)d_in[1];
    const float* bk   = (const float*)d_in[2];
    const float* Wq   = (const float*)d_in[3];
    const float* bq   = (const float*)d_in[4];
    const float* Wa1  = (const float*)d_in[5];
    const float* ba1  = (const float*)d_in[6];
    const float* ln_g = (const float*)d_in[7];
    const float* ln_b = (const float*)d_in[8];
    const float* Wa2  = (const float*)d_in[9];
    const float* ba2  = (const float*)d_in[10];
    const float* Wd   = (const float*)d_in[11];
    const float* bd   = (const float*)d_in[12];
    float* out = (float*)d_out;

    // ws layout: cm (B*T*D f32, reused as gate) | seg (B*T i32, also bind bits)
    //            | cs (B*(T+1) i32, ALSO reused as bf16 W-frag buffer after k_mean)
    char* ws = (char*)d_ws;
    float* cm = (float*)ws;
    int* seg  = (int*)(ws + (size_t)BB * TT * DD * 4);
    int* cs   = seg + BB * TT;
    int* numC = cs + BB * (TT + 1);
    ushort* wf = (ushort*)cs;   // 96 KB, alive only after k_mean

    k_bind<<<dim3(256, BB), 256, 0, stream>>>(x, Wk, bk, Wq, bq, seg);
    k_scan<<<dim3(BB), 1024, 0, stream>>>(seg, seg, cs, numC);
    k_mean<<<dim3(BB * TT / 4), 256, 0, stream>>>(x, cs, numC, cm);
    k_wprep<<<dim3(32, 3), 64, 0, stream>>>(Wa1, Wa2, Wd, wf);
    k_mlp<<<dim3(TT / 64, BB), 256, 0, stream>>>(ba1, ln_g, ln_b, ba2, bd, wf, numC, cm);
    k_out<<<dim3(BB * TT * DD / (256 * 4)), 256, 0, stream>>>(x, seg, cm, out);
}